// Round 3
// baseline (622.637 us; speedup 1.0000x reference)
//
#include <hip/hip_runtime.h>
#include <cstdint>

typedef __bf16 bf16;
typedef bf16 bf16x8 __attribute__((ext_vector_type(8)));
typedef bf16 bf16x4 __attribute__((ext_vector_type(4)));
typedef float f32x4 __attribute__((ext_vector_type(4)));
typedef uint32_t u32;

static constexpr int E_ = 1024;
static constexpr int H_ = 16;
static constexpr int DH_ = 64;
static constexpr int F_ = 4096;
static constexpr int B_ = 4;
static constexpr int S_ = 1024;
static constexpr long TOK = (long)B_ * S_;  // 4096 tokens

__device__ static __forceinline__ void gld16(const void* g, void* l) {
  __builtin_amdgcn_global_load_lds(
      (const __attribute__((address_space(1))) u32*)g,
      (__attribute__((address_space(3))) u32*)l, 16, 0, 0);
}

__device__ __forceinline__ f32x4 mfma16(bf16x8 a, bf16x8 b, f32x4 c) {
  return __builtin_amdgcn_mfma_f32_16x16x32_bf16(a, b, c, 0, 0, 0);
}

// ------------------------------------------------- f32 -> bf16 (all tensors)
__global__ __launch_bounds__(256) void f2b_all(
    const float* __restrict__ s0, bf16* __restrict__ d0,
    const float* __restrict__ s1, bf16* __restrict__ d1,
    const float* __restrict__ s2, bf16* __restrict__ d2,
    const float* __restrict__ s3, bf16* __restrict__ d3,
    const float* __restrict__ s4, bf16* __restrict__ d4) {
  long v = (long)blockIdx.x * 256 + threadIdx.x;
  const float* in;
  bf16* out;
  long off;
  if (v < 524288)        { in = s0; out = d0; off = v; }
  else if (v < 917504)   { in = s1; out = d1; off = v - 524288; }
  else if (v < 1048576)  { in = s2; out = d2; off = v - 917504; }
  else if (v < 1572864)  { in = s3; out = d3; off = v - 1048576; }
  else                   { in = s4; out = d4; off = v - 1572864; }
  const float4* p = (const float4*)in + off * 2;
  float4 a = p[0], b = p[1];
  bf16x8 o = {(bf16)a.x, (bf16)a.y, (bf16)a.z, (bf16)a.w,
              (bf16)b.x, (bf16)b.y, (bf16)b.z, (bf16)b.w};
  *((bf16x8*)out + off) = o;
}

// ------------------------------------------- 256x256 pipelined GEMM (NT)
// C[M,N] = A[M,K] * B[N,K]^T. 512 threads, 8 waves (2Mx4N), BK=64.
// Counted-vmcnt software pipeline (T3+T4): A-frags fully register-resident
// after phase 0 -> A(kt+2) prefetch into the SAME buffer from phase 1;
// B consumed per-phase -> B(kt+1) prefetch into the OTHER buffer at phase 0.
// Steady state at tile start: 12 loads outstanding; vmcnt(4) drains
// {A(kt), B(kt)}, leaves A(kt+1) in flight. Last tile: vmcnt(0).
enum { G_RELU_BF16 = 0, G_QKV = 1 };

template <int EPI>
__global__ __launch_bounds__(512, 2) void gemm256(
    const bf16* __restrict__ A, const bf16* __restrict__ Bm,
    bf16* __restrict__ Cb, bf16* __restrict__ Qh, bf16* __restrict__ Kh,
    bf16* __restrict__ Vt, const float* __restrict__ bias, int K, int ldc) {
  __shared__ bf16 S[65536];  // 128 KB: A0|A1|B0|B1, 32 KB each
  bf16* A0 = S;
  bf16* A1 = S + 16384;
  bf16* B0 = S + 32768;
  bf16* B1 = S + 49152;
  const int tid = threadIdx.x, lane = tid & 63, wave = tid >> 6;
  const int quad = lane >> 4, l16 = lane & 15;
  const int wm = wave >> 2, wn = wave & 3;
  const int row0 = blockIdx.y * 256, col0 = blockIdx.x * 256;
  const int NT = K >> 6;  // K-tiles (even, >= 4)

  const long ldab = (long)K * 2;
  const char* Ag = (const char*)A + (long)(row0 + (tid >> 3)) * ldab + (tid & 7) * 16;
  const char* Bg = (const char*)Bm + (long)(col0 + (tid >> 3)) * ldab + (tid & 7) * 16;
  char* A0c = (char*)A0 + tid * 16;
  char* A1c = (char*)A1 + tid * 16;
  char* B0c = (char*)B0 + tid * 16;
  char* B1c = (char*)B1 + tid * 16;

  f32x4 acc[8][4];
#pragma unroll
  for (int m = 0; m < 8; m++)
#pragma unroll
    for (int n = 0; n < 4; n++) acc[m][n] = (f32x4){0.f, 0.f, 0.f, 0.f};

  // prologue: A(0), B(0), A(1)  (oldest-first; 12 loads outstanding)
#pragma unroll
  for (int c = 0; c < 4; c++) gld16(Ag + (long)c * 64 * ldab, A0c + c * 8192);
#pragma unroll
  for (int c = 0; c < 4; c++) gld16(Bg + (long)c * 64 * ldab, B0c + c * 8192);
#pragma unroll
  for (int c = 0; c < 4; c++) gld16(Ag + (long)c * 64 * ldab + 128, A1c + c * 8192);

  auto tile = [&](int kt, const bf16* Ac, const bf16* Bc, char* AcS, char* BoS,
                  bool last) {
    if (last)
      asm volatile("s_waitcnt vmcnt(0)" ::: "memory");
    else
      asm volatile("s_waitcnt vmcnt(4)" ::: "memory");
    __builtin_amdgcn_s_barrier();
    // phase 0: issue B(kt+1) -> other buffer; consume ALL A-frags + B(n=0)
    if (kt + 1 < NT) {
#pragma unroll
      for (int c = 0; c < 4; c++)
        gld16(Bg + (long)c * 64 * ldab + (long)(kt + 1) * 128, BoS + c * 8192);
    }
    bf16x8 af[8][2], bfr[2];
#pragma unroll
    for (int m = 0; m < 8; m++)
#pragma unroll
      for (int kk = 0; kk < 2; kk++)
        af[m][kk] = *(const bf16x8*)&Ac[(wm * 128 + m * 16 + l16) * 64 + kk * 32 + quad * 8];
#pragma unroll
    for (int kk = 0; kk < 2; kk++)
      bfr[kk] = *(const bf16x8*)&Bc[(wn * 64 + l16) * 64 + kk * 32 + quad * 8];
    __builtin_amdgcn_s_setprio(1);
#pragma unroll
    for (int m = 0; m < 8; m++)
#pragma unroll
      for (int kk = 0; kk < 2; kk++)
        acc[m][0] = mfma16(af[m][kk], bfr[kk], acc[m][0]);
    __builtin_amdgcn_s_setprio(0);
    asm volatile("s_waitcnt lgkmcnt(0)" ::: "memory");
    __builtin_amdgcn_s_barrier();  // A-region consumption fence
    // phases 1..3: per-phase B-frag, A(kt+2) prefetch into CURRENT A buffer
#pragma unroll
    for (int n = 1; n < 4; n++) {
      if (n < 3 && kt + 2 < NT) {
#pragma unroll
        for (int c = 0; c < 2; c++) {
          int sw = (n - 1) * 2 + c;
          gld16(Ag + (long)sw * 64 * ldab + (long)(kt + 2) * 128, AcS + sw * 8192);
        }
      }
#pragma unroll
      for (int kk = 0; kk < 2; kk++)
        bfr[kk] = *(const bf16x8*)&Bc[(wn * 64 + n * 16 + l16) * 64 + kk * 32 + quad * 8];
      __builtin_amdgcn_s_setprio(1);
#pragma unroll
      for (int m = 0; m < 8; m++)
#pragma unroll
        for (int kk = 0; kk < 2; kk++)
          acc[m][n] = mfma16(af[m][kk], bfr[kk], acc[m][n]);
      __builtin_amdgcn_s_setprio(0);
    }
  };

  for (int kt = 0; kt < NT; kt += 2) {
    tile(kt, A0, B0, A0c, B1c, false);
    tile(kt + 1, A1, B1, A1c, B0c, kt + 2 == NT);
  }

  if constexpr (EPI == G_RELU_BF16) {
#pragma unroll
    for (int m = 0; m < 8; m++)
#pragma unroll
      for (int n = 0; n < 4; n++)
#pragma unroll
        for (int r = 0; r < 4; r++) {
          int row = row0 + wm * 128 + m * 16 + quad * 4 + r;
          int col = col0 + wn * 64 + n * 16 + l16;
          float v = acc[m][n][r] + bias[col];
          Cb[(long)row * ldc + col] = (bf16)fmaxf(v, 0.f);
        }
  } else {  // G_QKV scatter; `which` block-uniform (256 | 1024)
    const int which = col0 >> 10;
    if (which == 2) {
      // V: transpose via LDS (XOR swizzle), coalesced Vt stores.
      asm volatile("s_waitcnt lgkmcnt(0) vmcnt(0)" ::: "memory");
      __builtin_amdgcn_s_barrier();  // K-loop LDS fully done in all waves
      bf16* T = S;  // 256 cols x 256 rows bf16 = 128 KB
#pragma unroll
      for (int m = 0; m < 8; m++)
#pragma unroll
        for (int n = 0; n < 4; n++)
#pragma unroll
          for (int r = 0; r < 4; r++) {
            int row_l = wm * 128 + m * 16 + quad * 4 + r;
            int col_l = wn * 64 + n * 16 + l16;
            float t = acc[m][n][r] + bias[col0 + col_l];
            T[col_l * 256 + (row_l ^ ((col_l & 7) << 4))] = (bf16)t;
          }
      __syncthreads();
      const int b_ = row0 >> 10;
      const int s0 = row0 & 1023;
#pragma unroll
      for (int g = 0; g < 8; g++) {
        int col_l = wave * 32 + g * 4 + quad;
        int nn = (col0 + col_l) & 1023;
        int h_ = nn >> 6, d_ = nn & 63;
#pragma unroll
        for (int half = 0; half < 2; half++) {
          int sl = l16 * 8 + half * 128;
          bf16x8 vv = *(const bf16x8*)&T[col_l * 256 + (sl ^ ((col_l & 7) << 4))];
          *(bf16x8*)&Vt[(((long)(b_ * H_ + h_)) * DH_ + d_) * S_ + s0 + sl] = vv;
        }
      }
    } else {
#pragma unroll
      for (int m = 0; m < 8; m++)
#pragma unroll
        for (int n = 0; n < 4; n++)
#pragma unroll
          for (int r = 0; r < 4; r++) {
            int row = row0 + wm * 128 + m * 16 + quad * 4 + r;
            int col = col0 + wn * 64 + n * 16 + l16;
            float t = acc[m][n][r] + bias[col];
            int b_ = row >> 10, s_ = row & 1023;
            int nn = col & 1023;
            int h_ = nn >> 6, d_ = nn & 63;
            long q = (((long)(b_ * H_ + h_)) * S_ + s_) * DH_ + d_;
            if (which == 0) Qh[q] = (bf16)t;
            else Kh[q] = (bf16)t;
          }
    }
  }
}

// ---------------------------------------------------------------- GEMM (NT)
// 128xBN m97-style kernel, kept for the N=1024 GEMMs (grid at 256x256 tiles
// would be 64 blocks = 25% of the GPU).
enum { EPI_BIAS_RES_F32 = 3 };

template <int EPI, int BN>
__global__ __launch_bounds__(256, 2) void gemm_nt(
    const bf16* __restrict__ A, const bf16* __restrict__ Bm,
    float* __restrict__ Cf, bf16* __restrict__ Cb,
    const float* __restrict__ bias, const float* __restrict__ res,
    int K, int ldc) {
  constexpr int NJ = BN / 32;
  __shared__ bf16 Sm[128 * 64 + BN * 64];
  bf16* As = Sm;
  bf16* Bs = Sm + 128 * 64;
  const int tid = threadIdx.x, lane = tid & 63, wave = tid >> 6;
  const int quad = lane >> 4, l16 = lane & 15;
  const int wm = wave >> 1, wn = wave & 1;
  const int row0 = blockIdx.y * 128, col0 = blockIdx.x * BN;

  const long ldab = (long)K * 2;
  const char* Ag = (const char*)A +
                   (long)(row0 + wave * 32 + (lane >> 3)) * ldab + (lane & 7) * 16;
  const char* Bg = (const char*)Bm +
                   (long)(col0 + wave * (BN / 4) + (lane >> 3)) * ldab + (lane & 7) * 16;
  char* Al = (char*)As + (wave * 32 + (lane >> 3)) * 128 + (lane & 7) * 16;
  char* Bl = (char*)Bs + (wave * (BN / 4) + (lane >> 3)) * 128 + (lane & 7) * 16;

  f32x4 acc[4][NJ];
#pragma unroll
  for (int i = 0; i < 4; i++)
#pragma unroll
    for (int j = 0; j < NJ; j++) acc[i][j] = (f32x4){0.f, 0.f, 0.f, 0.f};

  for (int k0 = 0; k0 < K; k0 += 64) {
    __syncthreads();
#pragma unroll
    for (int c = 0; c < 4; c++) gld16(Ag + (long)c * 8 * ldab + k0 * 2, Al + c * 1024);
#pragma unroll
    for (int c = 0; c < BN / 32; c++) gld16(Bg + (long)c * 8 * ldab + k0 * 2, Bl + c * 1024);
    __syncthreads();
#pragma unroll
    for (int kk = 0; kk < 2; kk++) {
      bf16x8 af[4], bfr[NJ];
#pragma unroll
      for (int i = 0; i < 4; i++)
        af[i] = *(const bf16x8*)&As[(wm * 64 + i * 16 + l16) * 64 + kk * 32 + quad * 8];
#pragma unroll
      for (int j = 0; j < NJ; j++)
        bfr[j] = *(const bf16x8*)&Bs[(wn * (BN / 2) + j * 16 + l16) * 64 + kk * 32 + quad * 8];
#pragma unroll
      for (int i = 0; i < 4; i++)
#pragma unroll
        for (int j = 0; j < NJ; j++) acc[i][j] = mfma16(af[i], bfr[j], acc[i][j]);
    }
  }

#pragma unroll
  for (int i = 0; i < 4; i++)
#pragma unroll
    for (int j = 0; j < NJ; j++)
#pragma unroll
      for (int r = 0; r < 4; r++) {
        int row = row0 + wm * 64 + i * 16 + quad * 4 + r;
        int col = col0 + wn * (BN / 2) + j * 16 + l16;
        float v = acc[i][j][r];
        if constexpr (EPI == EPI_BIAS_RES_F32) {
          Cf[(long)row * ldc + col] = v + bias[col] + res[(long)row * ldc + col];
        } else {
          Cb[(long)row * ldc + col] = (bf16)fmaxf(v + bias[col], 0.f);
        }
      }
}

// --------------------------------------------------- fused attention, pass 1
__global__ __launch_bounds__(256, 2) void attn_pass1(
    const bf16* __restrict__ Q, const bf16* __restrict__ K,
    const float* __restrict__ mask, float* __restrict__ rowsum) {
  __shared__ bf16 Qs[128 * 64];
  __shared__ bf16 Ks[128 * 64];
  const int tid = threadIdx.x, lane = tid & 63, wave = tid >> 6;
  const int quad = lane >> 4, l16 = lane & 15;
  const int q0 = blockIdx.x * 128, bh = blockIdx.y;
  const bf16* Qb = Q + ((long)bh * S_ + q0) * DH_;
  const bf16* Kb = K + (long)bh * S_ * DH_;

  {
    const char* g = (const char*)Qb + wave * 4096 + lane * 16;
    char* l = (char*)Qs + wave * 4096 + lane * 16;
#pragma unroll
    for (int c = 0; c < 4; c++) gld16(g + c * 1024, l + c * 1024);
  }

  float rs[2][4];
#pragma unroll
  for (int i = 0; i < 2; i++)
#pragma unroll
    for (int r = 0; r < 4; r++) rs[i][r] = 0.f;

  for (int t = 0; t < 8; t++) {
    __syncthreads();
    {
      const char* g = (const char*)Kb + (long)t * 16384 + wave * 4096 + lane * 16;
      char* l = (char*)Ks + wave * 4096 + lane * 16;
#pragma unroll
      for (int c = 0; c < 4; c++) gld16(g + c * 1024, l + c * 1024);
    }
    __syncthreads();
    f32x4 acc[2][8];
#pragma unroll
    for (int i = 0; i < 2; i++)
#pragma unroll
      for (int j = 0; j < 8; j++) acc[i][j] = (f32x4){0.f, 0.f, 0.f, 0.f};
#pragma unroll
    for (int kk = 0; kk < 2; kk++) {
      bf16x8 af[2], bfr[8];
#pragma unroll
      for (int i = 0; i < 2; i++)
        af[i] = *(const bf16x8*)&Qs[(wave * 32 + i * 16 + l16) * 64 + kk * 32 + quad * 8];
#pragma unroll
      for (int j = 0; j < 8; j++)
        bfr[j] = *(const bf16x8*)&Ks[(j * 16 + l16) * 64 + kk * 32 + quad * 8];
#pragma unroll
      for (int i = 0; i < 2; i++)
#pragma unroll
        for (int j = 0; j < 8; j++) acc[i][j] = mfma16(af[i], bfr[j], acc[i][j]);
    }
#pragma unroll
    for (int i = 0; i < 2; i++)
#pragma unroll
      for (int j = 0; j < 8; j++)
#pragma unroll
        for (int r = 0; r < 4; r++) {
          int qr = q0 + wave * 32 + i * 16 + quad * 4 + r;
          int gcol = t * 128 + j * 16 + l16;
          float sv = acc[i][j][r] * 0.125f + mask[(long)qr * S_ + gcol];
          rs[i][r] += __expf(sv);
        }
  }
#pragma unroll
  for (int i = 0; i < 2; i++)
#pragma unroll
    for (int r = 0; r < 4; r++) {
      float v = rs[i][r];
      v += __shfl_xor(v, 1);
      v += __shfl_xor(v, 2);
      v += __shfl_xor(v, 4);
      v += __shfl_xor(v, 8);
      if (l16 == 0)
        rowsum[(long)bh * S_ + q0 + wave * 32 + i * 16 + quad * 4 + r] = v;
    }
}

// --------------------------------------------------- fused attention, pass 2
__global__ __launch_bounds__(256, 2) void attn_pass2(
    const bf16* __restrict__ Q, const bf16* __restrict__ K,
    const bf16* __restrict__ V, const float* __restrict__ mask,
    const float* __restrict__ rowsum, float* __restrict__ W,
    bf16* __restrict__ ctxb) {
  __shared__ bf16 Qs[128 * 64];
  __shared__ bf16 Ks[128 * 64];
  __shared__ bf16 Ps[128 * 136];
  const int tid = threadIdx.x, lane = tid & 63, wave = tid >> 6;
  const int quad = lane >> 4, l16 = lane & 15;
  const int q0 = blockIdx.x * 128, bh = blockIdx.y;
  const bf16* Qb = Q + ((long)bh * S_ + q0) * DH_;
  const bf16* Kb = K + (long)bh * S_ * DH_;
  const bf16* Vb = V + (long)bh * DH_ * S_;

  float rinv[2][4];
#pragma unroll
  for (int i = 0; i < 2; i++)
#pragma unroll
    for (int r = 0; r < 4; r++)
      rinv[i][r] =
          1.0f / rowsum[(long)bh * S_ + q0 + wave * 32 + i * 16 + quad * 4 + r];

  {
    const char* g = (const char*)Qb + wave * 4096 + lane * 16;
    char* l = (char*)Qs + wave * 4096 + lane * 16;
#pragma unroll
    for (int c = 0; c < 4; c++) gld16(g + c * 1024, l + c * 1024);
  }

  f32x4 cacc[2][4];
#pragma unroll
  for (int i = 0; i < 2; i++)
#pragma unroll
    for (int j = 0; j < 4; j++) cacc[i][j] = (f32x4){0.f, 0.f, 0.f, 0.f};

  for (int t = 0; t < 8; t++) {
    __syncthreads();
    {
      const char* g = (const char*)Kb + (long)t * 16384 + wave * 4096 + lane * 16;
      char* l = (char*)Ks + wave * 4096 + lane * 16;
#pragma unroll
      for (int c = 0; c < 4; c++) gld16(g + c * 1024, l + c * 1024);
    }
    __syncthreads();
    f32x4 acc[2][8];
#pragma unroll
    for (int i = 0; i < 2; i++)
#pragma unroll
      for (int j = 0; j < 8; j++) acc[i][j] = (f32x4){0.f, 0.f, 0.f, 0.f};
#pragma unroll
    for (int kk = 0; kk < 2; kk++) {
      bf16x8 af[2], bfr[8];
#pragma unroll
      for (int i = 0; i < 2; i++)
        af[i] = *(const bf16x8*)&Qs[(wave * 32 + i * 16 + l16) * 64 + kk * 32 + quad * 8];
#pragma unroll
      for (int j = 0; j < 8; j++)
        bfr[j] = *(const bf16x8*)&Ks[(j * 16 + l16) * 64 + kk * 32 + quad * 8];
#pragma unroll
      for (int i = 0; i < 2; i++)
#pragma unroll
        for (int j = 0; j < 8; j++) acc[i][j] = mfma16(af[i], bfr[j], acc[i][j]);
    }
#pragma unroll
    for (int i = 0; i < 2; i++)
#pragma unroll
      for (int j = 0; j < 8; j++)
#pragma unroll
        for (int r = 0; r < 4; r++) {
          int ql = wave * 32 + i * 16 + quad * 4 + r;
          int qr = q0 + ql;
          int col = j * 16 + l16, gcol = t * 128 + col;
          float u = __expf(acc[i][j][r] * 0.125f + mask[(long)qr * S_ + gcol]) *
                    rinv[i][r];
          __builtin_nontemporal_store(u, &W[((long)bh * S_ + qr) * S_ + gcol]);
          Ps[ql * 136 + col] = (bf16)u;
        }
    __syncthreads();
#pragma unroll
    for (int kk = 0; kk < 4; kk++) {
      bf16x8 pf[2], vf[4];
#pragma unroll
      for (int i = 0; i < 2; i++)
        pf[i] = *(const bf16x8*)&Ps[(wave * 32 + i * 16 + l16) * 136 + kk * 32 + quad * 8];
#pragma unroll
      for (int j = 0; j < 4; j++)
        vf[j] = *(const bf16x8*)(Vb + (long)(j * 16 + l16) * S_ + t * 128 +
                                 kk * 32 + quad * 8);
#pragma unroll
      for (int i = 0; i < 2; i++)
#pragma unroll
        for (int j = 0; j < 4; j++) cacc[i][j] = mfma16(pf[i], vf[j], cacc[i][j]);
    }
  }
  const int b_ = bh >> 4, h_ = bh & 15;
#pragma unroll
  for (int i = 0; i < 2; i++)
#pragma unroll
    for (int j = 0; j < 4; j++)
#pragma unroll
      for (int r = 0; r < 4; r++) {
        int qr = q0 + wave * 32 + i * 16 + quad * 4 + r;
        ctxb[((long)b_ * S_ + qr) * E_ + h_ * 64 + j * 16 + l16] =
            (bf16)cacc[i][j][r];
      }
}

// ------------------------------------------------------- layernorm (single in)
__global__ __launch_bounds__(256) void ln_kernel(
    const float* __restrict__ a, const float* __restrict__ g,
    const float* __restrict__ beta, float* __restrict__ outf,
    bf16* __restrict__ outb) {
  const int tid = threadIdx.x;
  const int wave = tid >> 6, lane = tid & 63;
  long base = (long)blockIdx.x * E_ + tid * 4;
  float4 x = *(const float4*)(a + base);
  float s = x.x + x.y + x.z + x.w;
  float sq = x.x * x.x + x.y * x.y + x.z * x.z + x.w * x.w;
#pragma unroll
  for (int o = 32; o; o >>= 1) { s += __shfl_xor(s, o); sq += __shfl_xor(sq, o); }
  __shared__ float rs[4], rq[4];
  if (!lane) { rs[wave] = s; rq[wave] = sq; }
  __syncthreads();
  s = rs[0] + rs[1] + rs[2] + rs[3];
  sq = rq[0] + rq[1] + rq[2] + rq[3];
  float mu = s * (1.f / E_);
  float var = sq * (1.f / E_) - mu * mu;
  float rstd = rsqrtf(var + 1e-5f);
  int c = tid * 4;
  float4 gg = *(const float4*)(g + c);
  float4 bb = *(const float4*)(beta + c);
  float o0 = (x.x - mu) * rstd * gg.x + bb.x;
  float o1 = (x.y - mu) * rstd * gg.y + bb.y;
  float o2 = (x.z - mu) * rstd * gg.z + bb.z;
  float o3 = (x.w - mu) * rstd * gg.w + bb.w;
  if (outf) *(float4*)(outf + base) = make_float4(o0, o1, o2, o3);
  if (outb) {
    bf16x4 ob = {(bf16)o0, (bf16)o1, (bf16)o2, (bf16)o3};
    *(bf16x4*)(outb + base) = ob;
  }
}

// ---------------------------------------------------------------- launch
extern "C" void kernel_launch(void* const* d_in, const int* in_sizes, int n_in,
                              void* d_out, int out_size, void* d_ws, size_t ws_size,
                              hipStream_t stream) {
  const float* src   = (const float*)d_in[0];
  const float* mask  = (const float*)d_in[1];
  const float* w_qkv = (const float*)d_in[2];
  const float* b_qkv = (const float*)d_in[3];
  const float* w_o   = (const float*)d_in[4];
  const float* b_o   = (const float*)d_in[5];
  const float* w1    = (const float*)d_in[6];
  const float* b1    = (const float*)d_in[7];
  const float* w2    = (const float*)d_in[8];
  const float* b2    = (const float*)d_in[9];
  const float* ln1g  = (const float*)d_in[10];
  const float* ln1b  = (const float*)d_in[11];
  const float* ln2g  = (const float*)d_in[12];
  const float* ln2b  = (const float*)d_in[13];

  float* out = (float*)d_out;
  float* attnW = out + TOK * E_;  // [B,H,S,S] fp32 (output 1)

  char* w = (char*)d_ws;
  auto alloc = [&](size_t bytes) {
    void* p = w;
    w += (bytes + 255) & ~(size_t)255;
    return p;
  };
  bf16* srcb  = (bf16*)alloc(TOK * E_ * 2);
  bf16* wqkvb = (bf16*)alloc((size_t)3 * E_ * E_ * 2);
  bf16* wob   = (bf16*)alloc((size_t)E_ * E_ * 2);
  bf16* w1b   = (bf16*)alloc((size_t)F_ * E_ * 2);
  bf16* w2b   = (bf16*)alloc((size_t)E_ * F_ * 2);
  bf16* Qh    = (bf16*)alloc((size_t)B_ * H_ * S_ * DH_ * 2);
  bf16* Kh    = (bf16*)alloc((size_t)B_ * H_ * S_ * DH_ * 2);
  bf16* Vt    = (bf16*)alloc((size_t)B_ * H_ * DH_ * S_ * 2);
  bf16* ctxb  = (bf16*)alloc(TOK * E_ * 2);
  float* attn_out = (float*)alloc(TOK * E_ * 4);
  float* x1f  = (float*)alloc(TOK * E_ * 4);
  bf16* x1b   = (bf16*)alloc(TOK * E_ * 2);
  bf16* h1b   = (bf16*)alloc(TOK * (size_t)F_ * 2);
  float* ffn2 = (float*)alloc(TOK * E_ * 4);
  float* rowsum = (float*)alloc((size_t)B_ * H_ * S_ * 4);

  f2b_all<<<8192, 256, 0, stream>>>(src, srcb, w_qkv, wqkvb, w_o, wob,
                                    w1, w1b, w2, w2b);

  // QKV projection -> Qh/Kh/Vt  (256-tile pipelined kernel, grid 12x16)
  gemm256<G_QKV><<<dim3(3 * E_ / 256, TOK / 256), 512, 0, stream>>>(
      srcb, wqkvb, nullptr, Qh, Kh, Vt, b_qkv, E_, 0);

  // fused attention
  attn_pass1<<<dim3(S_ / 128, B_ * H_), 256, 0, stream>>>(Qh, Kh, mask, rowsum);
  attn_pass2<<<dim3(S_ / 128, B_ * H_), 256, 0, stream>>>(Qh, Kh, Vt, mask,
                                                          rowsum, attnW, ctxb);

  // attn_out = ctx W_o^T + b_o + src   (residual fused; BN=64 -> 512 blocks)
  gemm_nt<EPI_BIAS_RES_F32, 64><<<dim3(E_ / 64, TOK / 128), 256, 0, stream>>>(
      ctxb, wob, attn_out, nullptr, b_o, src, E_, E_);

  // x1 = LN(attn_out)
  ln_kernel<<<TOK, 256, 0, stream>>>(attn_out, ln1g, ln1b, x1f, x1b);

  // h1 = relu(x1 W1^T + b1)  (256-tile pipelined kernel, grid 16x16)
  gemm256<G_RELU_BF16><<<dim3(F_ / 256, TOK / 256), 512, 0, stream>>>(
      x1b, w1b, h1b, nullptr, nullptr, nullptr, b1, E_, F_);

  // ffn2 = h1 W2^T + b2 + x1   (residual fused; BN=64 -> 512 blocks)
  gemm_nt<EPI_BIAS_RES_F32, 64><<<dim3(E_ / 64, TOK / 128), 256, 0, stream>>>(
      h1b, w2b, ffn2, nullptr, b2, x1f, F_, E_);

  // out = LN(ffn2)
  ln_kernel<<<TOK, 256, 0, stream>>>(ffn2, ln2g, ln2b, out, nullptr);
}

// Round 4
// 600.477 us; speedup vs baseline: 1.0369x; 1.0369x over previous
//
#include <hip/hip_runtime.h>
#include <cstdint>

typedef __bf16 bf16;
typedef bf16 bf16x8 __attribute__((ext_vector_type(8)));
typedef bf16 bf16x4 __attribute__((ext_vector_type(4)));
typedef float f32x4 __attribute__((ext_vector_type(4)));
typedef uint32_t u32;

static constexpr int E_ = 1024;
static constexpr int H_ = 16;
static constexpr int DH_ = 64;
static constexpr int F_ = 4096;
static constexpr int B_ = 4;
static constexpr int S_ = 1024;
static constexpr long TOK = (long)B_ * S_;  // 4096 tokens

__device__ static __forceinline__ void gld16(const void* g, void* l) {
  __builtin_amdgcn_global_load_lds(
      (const __attribute__((address_space(1))) u32*)g,
      (__attribute__((address_space(3))) u32*)l, 16, 0, 0);
}

__device__ __forceinline__ f32x4 mfma16(bf16x8 a, bf16x8 b, f32x4 c) {
  return __builtin_amdgcn_mfma_f32_16x16x32_bf16(a, b, c, 0, 0, 0);
}

// ------------------------------------------------- f32 -> bf16 (all tensors)
__global__ __launch_bounds__(256) void f2b_all(
    const float* __restrict__ s0, bf16* __restrict__ d0,
    const float* __restrict__ s1, bf16* __restrict__ d1,
    const float* __restrict__ s2, bf16* __restrict__ d2,
    const float* __restrict__ s3, bf16* __restrict__ d3,
    const float* __restrict__ s4, bf16* __restrict__ d4) {
  long v = (long)blockIdx.x * 256 + threadIdx.x;
  const float* in;
  bf16* out;
  long off;
  if (v < 524288)        { in = s0; out = d0; off = v; }
  else if (v < 917504)   { in = s1; out = d1; off = v - 524288; }
  else if (v < 1048576)  { in = s2; out = d2; off = v - 917504; }
  else if (v < 1572864)  { in = s3; out = d3; off = v - 1048576; }
  else                   { in = s4; out = d4; off = v - 1572864; }
  const float4* p = (const float4*)in + off * 2;
  float4 a = p[0], b = p[1];
  bf16x8 o = {(bf16)a.x, (bf16)a.y, (bf16)a.z, (bf16)a.w,
              (bf16)b.x, (bf16)b.y, (bf16)b.z, (bf16)b.w};
  *((bf16x8*)out + off) = o;
}

// ------------------------------------------- 256x256 pipelined GEMM (NT)
// Counted-vmcnt schedule (r3-verified accounting) + st_16x32-style LDS XOR
// swizzle (T2). gld16 writes LDS linearly, so the swizzle is pre-applied to
// the per-lane GLOBAL source address (involution; rule #21), and the same
// XOR is applied on ds_read addresses. 16-way bank conflict -> 4-way.
enum { G_RELU_BF16 = 0, G_QKV = 1 };

template <int EPI>
__global__ __launch_bounds__(512, 2) void gemm256(
    const bf16* __restrict__ A, const bf16* __restrict__ Bm,
    bf16* __restrict__ Cb, bf16* __restrict__ Qh, bf16* __restrict__ Kh,
    bf16* __restrict__ Vt, const float* __restrict__ bias, int K, int ldc) {
  __shared__ bf16 S[65536];  // 128 KB: A0|A1|B0|B1, 32 KB each
  bf16* A0 = S;
  bf16* A1 = S + 16384;
  bf16* B0 = S + 32768;
  bf16* B1 = S + 49152;
  const int tid = threadIdx.x, lane = tid & 63, wave = tid >> 6;
  const int quad = lane >> 4, l16 = lane & 15;
  const int wm = wave >> 2, wn = wave & 3;
  const int sx = ((l16 >> 2) & 1) << 4;  // read-side swizzle (bf16 elements)
  const int row0 = blockIdx.y * 256, col0 = blockIdx.x * 256;
  const int NT = K >> 6;  // K-tiles (even, >= 4)

  const long ldab = (long)K * 2;
  // source-side swizzle: LDS row = tid>>3 (mod 64 per stage group), its bit2
  // is (tid>>5)&1 -> XOR the 32B granule of the source column.
  const int cbs = ((tid & 7) * 16) ^ (((tid >> 5) & 1) << 5);
  const char* Ag = (const char*)A + (long)(row0 + (tid >> 3)) * ldab + cbs;
  const char* Bg = (const char*)Bm + (long)(col0 + (tid >> 3)) * ldab + cbs;
  char* A0c = (char*)A0 + tid * 16;
  char* A1c = (char*)A1 + tid * 16;
  char* B0c = (char*)B0 + tid * 16;
  char* B1c = (char*)B1 + tid * 16;

  f32x4 acc[8][4];
#pragma unroll
  for (int m = 0; m < 8; m++)
#pragma unroll
    for (int n = 0; n < 4; n++) acc[m][n] = (f32x4){0.f, 0.f, 0.f, 0.f};

  // prologue: A(0), B(0), A(1)  (12 instrs outstanding)
#pragma unroll
  for (int c = 0; c < 4; c++) gld16(Ag + (long)c * 64 * ldab, A0c + c * 8192);
#pragma unroll
  for (int c = 0; c < 4; c++) gld16(Bg + (long)c * 64 * ldab, B0c + c * 8192);
#pragma unroll
  for (int c = 0; c < 4; c++) gld16(Ag + (long)c * 64 * ldab + 128, A1c + c * 8192);

  auto tile = [&](int kt, const bf16* Ac, const bf16* Bc, char* AcS, char* BoS,
                  bool last) {
    // entry: drain {A(kt), B(kt)}; leave A(kt+1) in flight (4 instrs).
    if (last)
      asm volatile("s_waitcnt vmcnt(0)" ::: "memory");
    else
      asm volatile("s_waitcnt vmcnt(4)" ::: "memory");
    __builtin_amdgcn_sched_barrier(0);
    __builtin_amdgcn_s_barrier();
    __builtin_amdgcn_sched_barrier(0);
    bf16x8 af[4][2], bfr[4][2];
    // ---------------- half 0: A rows wm*128+0..63 ----------------
    if (kt + 1 < NT) {  // stage B(kt+1) half 0 -> other B buffer
      gld16(Bg + (long)(kt + 1) * 128, BoS);
      gld16(Bg + (long)64 * ldab + (long)(kt + 1) * 128, BoS + 8192);
    }
#pragma unroll
    for (int mi = 0; mi < 4; mi++)
#pragma unroll
      for (int kk = 0; kk < 2; kk++)
        af[mi][kk] = *(const bf16x8*)&Ac[(wm * 128 + mi * 16 + l16) * 64 +
                                         ((kk * 32 + quad * 8) ^ sx)];
#pragma unroll
    for (int n = 0; n < 4; n++) {
#pragma unroll
      for (int kk = 0; kk < 2; kk++)
        bfr[n][kk] = *(const bf16x8*)&Bc[(wn * 64 + n * 16 + l16) * 64 +
                                         ((kk * 32 + quad * 8) ^ sx)];
      __builtin_amdgcn_s_setprio(1);
#pragma unroll
      for (int mi = 0; mi < 4; mi++)
#pragma unroll
        for (int kk = 0; kk < 2; kk++)
          acc[mi][n] = mfma16(af[mi][kk], bfr[n][kk], acc[mi][n]);
      __builtin_amdgcn_s_setprio(0);
    }
    // ---------------- half 1: A rows wm*128+64..127 ----------------
    if (kt + 1 < NT) {  // stage B(kt+1) half 1
      gld16(Bg + (long)2 * 64 * ldab + (long)(kt + 1) * 128, BoS + 16384);
      gld16(Bg + (long)3 * 64 * ldab + (long)(kt + 1) * 128, BoS + 24576);
    }
#pragma unroll
    for (int mi = 0; mi < 4; mi++)
#pragma unroll
      for (int kk = 0; kk < 2; kk++)
        af[mi][kk] = *(const bf16x8*)&Ac[(wm * 128 + 64 + mi * 16 + l16) * 64 +
                                         ((kk * 32 + quad * 8) ^ sx)];
    // all Ac ds_reads (this tile, all waves) retired -> safe to overwrite Ac
    asm volatile("s_waitcnt lgkmcnt(0)" ::: "memory");
    __builtin_amdgcn_sched_barrier(0);
    __builtin_amdgcn_s_barrier();
    __builtin_amdgcn_sched_barrier(0);
#pragma unroll
    for (int n = 0; n < 4; n++) {
      if (n == 1 && kt + 2 < NT) {  // stage A(kt+2) half 0 into current buf
        gld16(Ag + (long)(kt + 2) * 128, AcS);
        gld16(Ag + (long)64 * ldab + (long)(kt + 2) * 128, AcS + 8192);
      }
      if (n == 2 && kt + 2 < NT) {  // stage A(kt+2) half 1
        gld16(Ag + (long)2 * 64 * ldab + (long)(kt + 2) * 128, AcS + 16384);
        gld16(Ag + (long)3 * 64 * ldab + (long)(kt + 2) * 128, AcS + 24576);
      }
      __builtin_amdgcn_s_setprio(1);
#pragma unroll
      for (int mi = 0; mi < 4; mi++)
#pragma unroll
        for (int kk = 0; kk < 2; kk++)
          acc[4 + mi][n] = mfma16(af[mi][kk], bfr[n][kk], acc[4 + mi][n]);
      __builtin_amdgcn_s_setprio(0);
    }
  };

  for (int kt = 0; kt < NT; kt += 2) {
    tile(kt, A0, B0, A0c, B1c, false);
    tile(kt + 1, A1, B1, A1c, B0c, kt + 2 == NT);
  }

  if constexpr (EPI == G_RELU_BF16) {
#pragma unroll
    for (int m = 0; m < 8; m++)
#pragma unroll
      for (int n = 0; n < 4; n++)
#pragma unroll
        for (int r = 0; r < 4; r++) {
          int row = row0 + wm * 128 + m * 16 + quad * 4 + r;
          int col = col0 + wn * 64 + n * 16 + l16;
          float v = acc[m][n][r] + bias[col];
          Cb[(long)row * ldc + col] = (bf16)fmaxf(v, 0.f);
        }
  } else {  // G_QKV scatter; `which` block-uniform (256 | 1024)
    const int which = col0 >> 10;
    if (which == 2) {
      // V: transpose via LDS (own XOR swizzle), coalesced Vt stores.
      asm volatile("s_waitcnt lgkmcnt(0) vmcnt(0)" ::: "memory");
      __builtin_amdgcn_s_barrier();  // K-loop LDS fully done in all waves
      bf16* T = S;  // 256 cols x 256 rows bf16 = 128 KB
#pragma unroll
      for (int m = 0; m < 8; m++)
#pragma unroll
        for (int n = 0; n < 4; n++)
#pragma unroll
          for (int r = 0; r < 4; r++) {
            int row_l = wm * 128 + m * 16 + quad * 4 + r;
            int col_l = wn * 64 + n * 16 + l16;
            float t = acc[m][n][r] + bias[col0 + col_l];
            T[col_l * 256 + (row_l ^ ((col_l & 7) << 4))] = (bf16)t;
          }
      __syncthreads();
      const int b_ = row0 >> 10;
      const int s0 = row0 & 1023;
#pragma unroll
      for (int g = 0; g < 8; g++) {
        int col_l = wave * 32 + g * 4 + quad;
        int nn = (col0 + col_l) & 1023;
        int h_ = nn >> 6, d_ = nn & 63;
#pragma unroll
        for (int half = 0; half < 2; half++) {
          int sl = l16 * 8 + half * 128;
          bf16x8 vv = *(const bf16x8*)&T[col_l * 256 + (sl ^ ((col_l & 7) << 4))];
          *(bf16x8*)&Vt[(((long)(b_ * H_ + h_)) * DH_ + d_) * S_ + s0 + sl] = vv;
        }
      }
    } else {
#pragma unroll
      for (int m = 0; m < 8; m++)
#pragma unroll
        for (int n = 0; n < 4; n++)
#pragma unroll
          for (int r = 0; r < 4; r++) {
            int row = row0 + wm * 128 + m * 16 + quad * 4 + r;
            int col = col0 + wn * 64 + n * 16 + l16;
            float t = acc[m][n][r] + bias[col];
            int b_ = row >> 10, s_ = row & 1023;
            int nn = col & 1023;
            int h_ = nn >> 6, d_ = nn & 63;
            long q = (((long)(b_ * H_ + h_)) * S_ + s_) * DH_ + d_;
            if (which == 0) Qh[q] = (bf16)t;
            else Kh[q] = (bf16)t;
          }
    }
  }
}

// ---------------------------------------------------------------- GEMM (NT)
// 128xBN m97-style kernel for the N=1024 GEMMs (2-phase regime: T2 null here,
// left unswizzled per the regime gate).
enum { EPI_BIAS_RES_F32 = 3 };

template <int EPI, int BN>
__global__ __launch_bounds__(256, 2) void gemm_nt(
    const bf16* __restrict__ A, const bf16* __restrict__ Bm,
    float* __restrict__ Cf, bf16* __restrict__ Cb,
    const float* __restrict__ bias, const float* __restrict__ res,
    int K, int ldc) {
  constexpr int NJ = BN / 32;
  __shared__ bf16 Sm[128 * 64 + BN * 64];
  bf16* As = Sm;
  bf16* Bs = Sm + 128 * 64;
  const int tid = threadIdx.x, lane = tid & 63, wave = tid >> 6;
  const int quad = lane >> 4, l16 = lane & 15;
  const int wm = wave >> 1, wn = wave & 1;
  const int row0 = blockIdx.y * 128, col0 = blockIdx.x * BN;

  const long ldab = (long)K * 2;
  const char* Ag = (const char*)A +
                   (long)(row0 + wave * 32 + (lane >> 3)) * ldab + (lane & 7) * 16;
  const char* Bg = (const char*)Bm +
                   (long)(col0 + wave * (BN / 4) + (lane >> 3)) * ldab + (lane & 7) * 16;
  char* Al = (char*)As + (wave * 32 + (lane >> 3)) * 128 + (lane & 7) * 16;
  char* Bl = (char*)Bs + (wave * (BN / 4) + (lane >> 3)) * 128 + (lane & 7) * 16;

  f32x4 acc[4][NJ];
#pragma unroll
  for (int i = 0; i < 4; i++)
#pragma unroll
    for (int j = 0; j < NJ; j++) acc[i][j] = (f32x4){0.f, 0.f, 0.f, 0.f};

  for (int k0 = 0; k0 < K; k0 += 64) {
    __syncthreads();
#pragma unroll
    for (int c = 0; c < 4; c++) gld16(Ag + (long)c * 8 * ldab + k0 * 2, Al + c * 1024);
#pragma unroll
    for (int c = 0; c < BN / 32; c++) gld16(Bg + (long)c * 8 * ldab + k0 * 2, Bl + c * 1024);
    __syncthreads();
#pragma unroll
    for (int kk = 0; kk < 2; kk++) {
      bf16x8 af[4], bfr[NJ];
#pragma unroll
      for (int i = 0; i < 4; i++)
        af[i] = *(const bf16x8*)&As[(wm * 64 + i * 16 + l16) * 64 + kk * 32 + quad * 8];
#pragma unroll
      for (int j = 0; j < NJ; j++)
        bfr[j] = *(const bf16x8*)&Bs[(wn * (BN / 2) + j * 16 + l16) * 64 + kk * 32 + quad * 8];
#pragma unroll
      for (int i = 0; i < 4; i++)
#pragma unroll
        for (int j = 0; j < NJ; j++) acc[i][j] = mfma16(af[i], bfr[j], acc[i][j]);
    }
  }

#pragma unroll
  for (int i = 0; i < 4; i++)
#pragma unroll
    for (int j = 0; j < NJ; j++)
#pragma unroll
      for (int r = 0; r < 4; r++) {
        int row = row0 + wm * 64 + i * 16 + quad * 4 + r;
        int col = col0 + wn * (BN / 2) + j * 16 + l16;
        float v = acc[i][j][r];
        if constexpr (EPI == EPI_BIAS_RES_F32) {
          Cf[(long)row * ldc + col] = v + bias[col] + res[(long)row * ldc + col];
        } else {
          Cb[(long)row * ldc + col] = (bf16)fmaxf(v + bias[col], 0.f);
        }
      }
}

// --------------------------------------------------- fused attention, pass 1
__global__ __launch_bounds__(256, 2) void attn_pass1(
    const bf16* __restrict__ Q, const bf16* __restrict__ K,
    const float* __restrict__ mask, float* __restrict__ rowsum) {
  __shared__ bf16 Qs[128 * 64];
  __shared__ bf16 Ks[128 * 64];
  const int tid = threadIdx.x, lane = tid & 63, wave = tid >> 6;
  const int quad = lane >> 4, l16 = lane & 15;
  const int q0 = blockIdx.x * 128, bh = blockIdx.y;
  const bf16* Qb = Q + ((long)bh * S_ + q0) * DH_;
  const bf16* Kb = K + (long)bh * S_ * DH_;

  {
    const char* g = (const char*)Qb + wave * 4096 + lane * 16;
    char* l = (char*)Qs + wave * 4096 + lane * 16;
#pragma unroll
    for (int c = 0; c < 4; c++) gld16(g + c * 1024, l + c * 1024);
  }

  float rs[2][4];
#pragma unroll
  for (int i = 0; i < 2; i++)
#pragma unroll
    for (int r = 0; r < 4; r++) rs[i][r] = 0.f;

  for (int t = 0; t < 8; t++) {
    __syncthreads();
    {
      const char* g = (const char*)Kb + (long)t * 16384 + wave * 4096 + lane * 16;
      char* l = (char*)Ks + wave * 4096 + lane * 16;
#pragma unroll
      for (int c = 0; c < 4; c++) gld16(g + c * 1024, l + c * 1024);
    }
    __syncthreads();
    f32x4 acc[2][8];
#pragma unroll
    for (int i = 0; i < 2; i++)
#pragma unroll
      for (int j = 0; j < 8; j++) acc[i][j] = (f32x4){0.f, 0.f, 0.f, 0.f};
#pragma unroll
    for (int kk = 0; kk < 2; kk++) {
      bf16x8 af[2], bfr[8];
#pragma unroll
      for (int i = 0; i < 2; i++)
        af[i] = *(const bf16x8*)&Qs[(wave * 32 + i * 16 + l16) * 64 + kk * 32 + quad * 8];
#pragma unroll
      for (int j = 0; j < 8; j++)
        bfr[j] = *(const bf16x8*)&Ks[(j * 16 + l16) * 64 + kk * 32 + quad * 8];
#pragma unroll
      for (int i = 0; i < 2; i++)
#pragma unroll
        for (int j = 0; j < 8; j++) acc[i][j] = mfma16(af[i], bfr[j], acc[i][j]);
    }
#pragma unroll
    for (int i = 0; i < 2; i++)
#pragma unroll
      for (int j = 0; j < 8; j++)
#pragma unroll
        for (int r = 0; r < 4; r++) {
          int qr = q0 + wave * 32 + i * 16 + quad * 4 + r;
          int gcol = t * 128 + j * 16 + l16;
          float sv = acc[i][j][r] * 0.125f + mask[(long)qr * S_ + gcol];
          rs[i][r] += __expf(sv);
        }
  }
#pragma unroll
  for (int i = 0; i < 2; i++)
#pragma unroll
    for (int r = 0; r < 4; r++) {
      float v = rs[i][r];
      v += __shfl_xor(v, 1);
      v += __shfl_xor(v, 2);
      v += __shfl_xor(v, 4);
      v += __shfl_xor(v, 8);
      if (l16 == 0)
        rowsum[(long)bh * S_ + q0 + wave * 32 + i * 16 + quad * 4 + r] = v;
    }
}

// --------------------------------------------------- fused attention, pass 2
__global__ __launch_bounds__(256, 2) void attn_pass2(
    const bf16* __restrict__ Q, const bf16* __restrict__ K,
    const bf16* __restrict__ V, const float* __restrict__ mask,
    const float* __restrict__ rowsum, float* __restrict__ W,
    bf16* __restrict__ ctxb) {
  __shared__ bf16 Qs[128 * 64];
  __shared__ bf16 Ks[128 * 64];
  __shared__ bf16 Ps[128 * 136];
  const int tid = threadIdx.x, lane = tid & 63, wave = tid >> 6;
  const int quad = lane >> 4, l16 = lane & 15;
  const int q0 = blockIdx.x * 128, bh = blockIdx.y;
  const bf16* Qb = Q + ((long)bh * S_ + q0) * DH_;
  const bf16* Kb = K + (long)bh * S_ * DH_;
  const bf16* Vb = V + (long)bh * DH_ * S_;

  float rinv[2][4];
#pragma unroll
  for (int i = 0; i < 2; i++)
#pragma unroll
    for (int r = 0; r < 4; r++)
      rinv[i][r] =
          1.0f / rowsum[(long)bh * S_ + q0 + wave * 32 + i * 16 + quad * 4 + r];

  {
    const char* g = (const char*)Qb + wave * 4096 + lane * 16;
    char* l = (char*)Qs + wave * 4096 + lane * 16;
#pragma unroll
    for (int c = 0; c < 4; c++) gld16(g + c * 1024, l + c * 1024);
  }

  f32x4 cacc[2][4];
#pragma unroll
  for (int i = 0; i < 2; i++)
#pragma unroll
    for (int j = 0; j < 4; j++) cacc[i][j] = (f32x4){0.f, 0.f, 0.f, 0.f};

  for (int t = 0; t < 8; t++) {
    __syncthreads();
    {
      const char* g = (const char*)Kb + (long)t * 16384 + wave * 4096 + lane * 16;
      char* l = (char*)Ks + wave * 4096 + lane * 16;
#pragma unroll
      for (int c = 0; c < 4; c++) gld16(g + c * 1024, l + c * 1024);
    }
    __syncthreads();
    f32x4 acc[2][8];
#pragma unroll
    for (int i = 0; i < 2; i++)
#pragma unroll
      for (int j = 0; j < 8; j++) acc[i][j] = (f32x4){0.f, 0.f, 0.f, 0.f};
#pragma unroll
    for (int kk = 0; kk < 2; kk++) {
      bf16x8 af[2], bfr[8];
#pragma unroll
      for (int i = 0; i < 2; i++)
        af[i] = *(const bf16x8*)&Qs[(wave * 32 + i * 16 + l16) * 64 + kk * 32 + quad * 8];
#pragma unroll
      for (int j = 0; j < 8; j++)
        bfr[j] = *(const bf16x8*)&Ks[(j * 16 + l16) * 64 + kk * 32 + quad * 8];
#pragma unroll
      for (int i = 0; i < 2; i++)
#pragma unroll
        for (int j = 0; j < 8; j++) acc[i][j] = mfma16(af[i], bfr[j], acc[i][j]);
    }
#pragma unroll
    for (int i = 0; i < 2; i++)
#pragma unroll
      for (int j = 0; j < 8; j++)
#pragma unroll
        for (int r = 0; r < 4; r++) {
          int ql = wave * 32 + i * 16 + quad * 4 + r;
          int qr = q0 + ql;
          int col = j * 16 + l16, gcol = t * 128 + col;
          float u = __expf(acc[i][j][r] * 0.125f + mask[(long)qr * S_ + gcol]) *
                    rinv[i][r];
          __builtin_nontemporal_store(u, &W[((long)bh * S_ + qr) * S_ + gcol]);
          Ps[ql * 136 + col] = (bf16)u;
        }
    __syncthreads();
#pragma unroll
    for (int kk = 0; kk < 4; kk++) {
      bf16x8 pf[2], vf[4];
#pragma unroll
      for (int i = 0; i < 2; i++)
        pf[i] = *(const bf16x8*)&Ps[(wave * 32 + i * 16 + l16) * 136 + kk * 32 + quad * 8];
#pragma unroll
      for (int j = 0; j < 4; j++)
        vf[j] = *(const bf16x8*)(Vb + (long)(j * 16 + l16) * S_ + t * 128 +
                                 kk * 32 + quad * 8);
#pragma unroll
      for (int i = 0; i < 2; i++)
#pragma unroll
        for (int j = 0; j < 4; j++) cacc[i][j] = mfma16(pf[i], vf[j], cacc[i][j]);
    }
  }
  const int b_ = bh >> 4, h_ = bh & 15;
#pragma unroll
  for (int i = 0; i < 2; i++)
#pragma unroll
    for (int j = 0; j < 4; j++)
#pragma unroll
      for (int r = 0; r < 4; r++) {
        int qr = q0 + wave * 32 + i * 16 + quad * 4 + r;
        ctxb[((long)b_ * S_ + qr) * E_ + h_ * 64 + j * 16 + l16] =
            (bf16)cacc[i][j][r];
      }
}

// ------------------------------------------------------- layernorm (single in)
__global__ __launch_bounds__(256) void ln_kernel(
    const float* __restrict__ a, const float* __restrict__ g,
    const float* __restrict__ beta, float* __restrict__ outf,
    bf16* __restrict__ outb) {
  const int tid = threadIdx.x;
  const int wave = tid >> 6, lane = tid & 63;
  long base = (long)blockIdx.x * E_ + tid * 4;
  float4 x = *(const float4*)(a + base);
  float s = x.x + x.y + x.z + x.w;
  float sq = x.x * x.x + x.y * x.y + x.z * x.z + x.w * x.w;
#pragma unroll
  for (int o = 32; o; o >>= 1) { s += __shfl_xor(s, o); sq += __shfl_xor(sq, o); }
  __shared__ float rs[4], rq[4];
  if (!lane) { rs[wave] = s; rq[wave] = sq; }
  __syncthreads();
  s = rs[0] + rs[1] + rs[2] + rs[3];
  sq = rq[0] + rq[1] + rq[2] + rq[3];
  float mu = s * (1.f / E_);
  float var = sq * (1.f / E_) - mu * mu;
  float rstd = rsqrtf(var + 1e-5f);
  int c = tid * 4;
  float4 gg = *(const float4*)(g + c);
  float4 bb = *(const float4*)(beta + c);
  float o0 = (x.x - mu) * rstd * gg.x + bb.x;
  float o1 = (x.y - mu) * rstd * gg.y + bb.y;
  float o2 = (x.z - mu) * rstd * gg.z + bb.z;
  float o3 = (x.w - mu) * rstd * gg.w + bb.w;
  if (outf) *(float4*)(outf + base) = make_float4(o0, o1, o2, o3);
  if (outb) {
    bf16x4 ob = {(bf16)o0, (bf16)o1, (bf16)o2, (bf16)o3};
    *(bf16x4*)(outb + base) = ob;
  }
}

// ---------------------------------------------------------------- launch
extern "C" void kernel_launch(void* const* d_in, const int* in_sizes, int n_in,
                              void* d_out, int out_size, void* d_ws, size_t ws_size,
                              hipStream_t stream) {
  const float* src   = (const float*)d_in[0];
  const float* mask  = (const float*)d_in[1];
  const float* w_qkv = (const float*)d_in[2];
  const float* b_qkv = (const float*)d_in[3];
  const float* w_o   = (const float*)d_in[4];
  const float* b_o   = (const float*)d_in[5];
  const float* w1    = (const float*)d_in[6];
  const float* b1    = (const float*)d_in[7];
  const float* w2    = (const float*)d_in[8];
  const float* b2    = (const float*)d_in[9];
  const float* ln1g  = (const float*)d_in[10];
  const float* ln1b  = (const float*)d_in[11];
  const float* ln2g  = (const float*)d_in[12];
  const float* ln2b  = (const float*)d_in[13];

  float* out = (float*)d_out;
  float* attnW = out + TOK * E_;  // [B,H,S,S] fp32 (output 1)

  char* w = (char*)d_ws;
  auto alloc = [&](size_t bytes) {
    void* p = w;
    w += (bytes + 255) & ~(size_t)255;
    return p;
  };
  bf16* srcb  = (bf16*)alloc(TOK * E_ * 2);
  bf16* wqkvb = (bf16*)alloc((size_t)3 * E_ * E_ * 2);
  bf16* wob   = (bf16*)alloc((size_t)E_ * E_ * 2);
  bf16* w1b   = (bf16*)alloc((size_t)F_ * E_ * 2);
  bf16* w2b   = (bf16*)alloc((size_t)E_ * F_ * 2);
  bf16* Qh    = (bf16*)alloc((size_t)B_ * H_ * S_ * DH_ * 2);
  bf16* Kh    = (bf16*)alloc((size_t)B_ * H_ * S_ * DH_ * 2);
  bf16* Vt    = (bf16*)alloc((size_t)B_ * H_ * DH_ * S_ * 2);
  bf16* ctxb  = (bf16*)alloc(TOK * E_ * 2);
  float* attn_out = (float*)alloc(TOK * E_ * 4);
  float* x1f  = (float*)alloc(TOK * E_ * 4);
  bf16* x1b   = (bf16*)alloc(TOK * E_ * 2);
  bf16* h1b   = (bf16*)alloc(TOK * (size_t)F_ * 2);
  float* ffn2 = (float*)alloc(TOK * E_ * 4);
  float* rowsum = (float*)alloc((size_t)B_ * H_ * S_ * 4);

  f2b_all<<<8192, 256, 0, stream>>>(src, srcb, w_qkv, wqkvb, w_o, wob,
                                    w1, w1b, w2, w2b);

  // QKV projection -> Qh/Kh/Vt  (256-tile pipelined kernel, grid 12x16)
  gemm256<G_QKV><<<dim3(3 * E_ / 256, TOK / 256), 512, 0, stream>>>(
      srcb, wqkvb, nullptr, Qh, Kh, Vt, b_qkv, E_, 0);

  // fused attention
  attn_pass1<<<dim3(S_ / 128, B_ * H_), 256, 0, stream>>>(Qh, Kh, mask, rowsum);
  attn_pass2<<<dim3(S_ / 128, B_ * H_), 256, 0, stream>>>(Qh, Kh, Vt, mask,
                                                          rowsum, attnW, ctxb);

  // attn_out = ctx W_o^T + b_o + src   (residual fused; BN=64 -> 512 blocks)
  gemm_nt<EPI_BIAS_RES_F32, 64><<<dim3(E_ / 64, TOK / 128), 256, 0, stream>>>(
      ctxb, wob, attn_out, nullptr, b_o, src, E_, E_);

  // x1 = LN(attn_out)
  ln_kernel<<<TOK, 256, 0, stream>>>(attn_out, ln1g, ln1b, x1f, x1b);

  // h1 = relu(x1 W1^T + b1)  (256-tile pipelined kernel, grid 16x16)
  gemm256<G_RELU_BF16><<<dim3(F_ / 256, TOK / 256), 512, 0, stream>>>(
      x1b, w1b, h1b, nullptr, nullptr, nullptr, b1, E_, F_);

  // ffn2 = h1 W2^T + b2 + x1   (residual fused; BN=64 -> 512 blocks)
  gemm_nt<EPI_BIAS_RES_F32, 64><<<dim3(E_ / 64, TOK / 128), 256, 0, stream>>>(
      h1b, w2b, ffn2, nullptr, b2, x1f, F_, E_);

  // out = LN(ffn2)
  ln_kernel<<<TOK, 256, 0, stream>>>(ffn2, ln2g, ln2b, out, nullptr);
}

// Round 5
// 564.350 us; speedup vs baseline: 1.1033x; 1.0640x over previous
//
#include <hip/hip_runtime.h>
#include <cstdint>

typedef __bf16 bf16;
typedef bf16 bf16x8 __attribute__((ext_vector_type(8)));
typedef bf16 bf16x4 __attribute__((ext_vector_type(4)));
typedef float f32x4 __attribute__((ext_vector_type(4)));
typedef uint32_t u32;

static constexpr int E_ = 1024;
static constexpr int H_ = 16;
static constexpr int DH_ = 64;
static constexpr int F_ = 4096;
static constexpr int B_ = 4;
static constexpr int S_ = 1024;
static constexpr long TOK = (long)B_ * S_;  // 4096 tokens

__device__ static __forceinline__ void gld16(const void* g, void* l) {
  __builtin_amdgcn_global_load_lds(
      (const __attribute__((address_space(1))) u32*)g,
      (__attribute__((address_space(3))) u32*)l, 16, 0, 0);
}

__device__ __forceinline__ f32x4 mfma16(bf16x8 a, bf16x8 b, f32x4 c) {
  return __builtin_amdgcn_mfma_f32_16x16x32_bf16(a, b, c, 0, 0, 0);
}

// ------------------------------------------------- f32 -> bf16 (all tensors)
__global__ __launch_bounds__(256) void f2b_all(
    const float* __restrict__ s0, bf16* __restrict__ d0,
    const float* __restrict__ s1, bf16* __restrict__ d1,
    const float* __restrict__ s2, bf16* __restrict__ d2,
    const float* __restrict__ s3, bf16* __restrict__ d3,
    const float* __restrict__ s4, bf16* __restrict__ d4) {
  long v = (long)blockIdx.x * 256 + threadIdx.x;
  const float* in;
  bf16* out;
  long off;
  if (v < 524288)        { in = s0; out = d0; off = v; }
  else if (v < 917504)   { in = s1; out = d1; off = v - 524288; }
  else if (v < 1048576)  { in = s2; out = d2; off = v - 917504; }
  else if (v < 1572864)  { in = s3; out = d3; off = v - 1048576; }
  else                   { in = s4; out = d4; off = v - 1572864; }
  const float4* p = (const float4*)in + off * 2;
  float4 a = p[0], b = p[1];
  bf16x8 o = {(bf16)a.x, (bf16)a.y, (bf16)a.z, (bf16)a.w,
              (bf16)b.x, (bf16)b.y, (bf16)b.z, (bf16)b.w};
  *((bf16x8*)out + off) = o;
}

// ------------------------------------------- 256x256 pipelined GEMM (NT)
// Counted-vmcnt schedule + FULL granule^=(row&7) LDS swizzle (T2).
// LDS[row][g] holds global[row][g ^ (row&7)] (granule = 16B). Source side
// pre-applies the involution (gld16 writes linearly, rule #21); reads XOR
// the same. Bank load: 8 accesses/bank = theoretical minimum.
enum { G_RELU_BF16 = 0, G_QKV = 1 };

template <int EPI>
__global__ __launch_bounds__(512, 2) void gemm256(
    const bf16* __restrict__ A, const bf16* __restrict__ Bm,
    bf16* __restrict__ Cb, bf16* __restrict__ Qh, bf16* __restrict__ Kh,
    bf16* __restrict__ Vt, const float* __restrict__ bias, int K, int ldc) {
  __shared__ bf16 S[65536];  // 128 KB: A0|A1|B0|B1, 32 KB each
  bf16* A0 = S;
  bf16* A1 = S + 16384;
  bf16* B0 = S + 32768;
  bf16* B1 = S + 49152;
  const int tid = threadIdx.x, lane = tid & 63, wave = tid >> 6;
  const int quad = lane >> 4, l16 = lane & 15;
  const int wm = wave >> 2, wn = wave & 3;
  const int sx = (l16 & 7) << 3;  // read-side granule swizzle (elem units)
  const int row0 = blockIdx.y * 256, col0 = blockIdx.x * 256;
  const int NT = K >> 6;  // K-tiles (even, >= 4)

  const long ldab = (long)K * 2;
  // source-side: column granule = (tid&7) ^ (ldsrow&7), ldsrow = tid>>3
  const int cbs = (((tid & 7) ^ ((tid >> 3) & 7))) * 16;
  const char* Ag = (const char*)A + (long)(row0 + (tid >> 3)) * ldab + cbs;
  const char* Bg = (const char*)Bm + (long)(col0 + (tid >> 3)) * ldab + cbs;
  char* A0c = (char*)A0 + tid * 16;
  char* A1c = (char*)A1 + tid * 16;
  char* B0c = (char*)B0 + tid * 16;
  char* B1c = (char*)B1 + tid * 16;

  f32x4 acc[8][4];
#pragma unroll
  for (int m = 0; m < 8; m++)
#pragma unroll
    for (int n = 0; n < 4; n++) acc[m][n] = (f32x4){0.f, 0.f, 0.f, 0.f};

  // prologue: A(0), B(0), A(1)  (12 instrs outstanding)
#pragma unroll
  for (int c = 0; c < 4; c++) gld16(Ag + (long)c * 64 * ldab, A0c + c * 8192);
#pragma unroll
  for (int c = 0; c < 4; c++) gld16(Bg + (long)c * 64 * ldab, B0c + c * 8192);
#pragma unroll
  for (int c = 0; c < 4; c++) gld16(Ag + (long)c * 64 * ldab + 128, A1c + c * 8192);

  auto tile = [&](int kt, const bf16* Ac, const bf16* Bc, char* AcS, char* BoS,
                  bool last) {
    // entry: drain {A(kt), B(kt)}; leave A(kt+1) in flight (4 instrs).
    if (last)
      asm volatile("s_waitcnt vmcnt(0)" ::: "memory");
    else
      asm volatile("s_waitcnt vmcnt(4)" ::: "memory");
    __builtin_amdgcn_sched_barrier(0);
    __builtin_amdgcn_s_barrier();
    __builtin_amdgcn_sched_barrier(0);
    bf16x8 af[4][2], bfr[4][2];
    // ---------------- half 0: A rows wm*128+0..63 ----------------
    if (kt + 1 < NT) {  // stage B(kt+1) half 0 -> other B buffer
      gld16(Bg + (long)(kt + 1) * 128, BoS);
      gld16(Bg + (long)64 * ldab + (long)(kt + 1) * 128, BoS + 8192);
    }
#pragma unroll
    for (int mi = 0; mi < 4; mi++)
#pragma unroll
      for (int kk = 0; kk < 2; kk++)
        af[mi][kk] = *(const bf16x8*)&Ac[(wm * 128 + mi * 16 + l16) * 64 +
                                         ((kk * 32 + quad * 8) ^ sx)];
#pragma unroll
    for (int n = 0; n < 4; n++) {
#pragma unroll
      for (int kk = 0; kk < 2; kk++)
        bfr[n][kk] = *(const bf16x8*)&Bc[(wn * 64 + n * 16 + l16) * 64 +
                                         ((kk * 32 + quad * 8) ^ sx)];
      __builtin_amdgcn_s_setprio(1);
#pragma unroll
      for (int mi = 0; mi < 4; mi++)
#pragma unroll
        for (int kk = 0; kk < 2; kk++)
          acc[mi][n] = mfma16(af[mi][kk], bfr[n][kk], acc[mi][n]);
      __builtin_amdgcn_s_setprio(0);
    }
    // ---------------- half 1: A rows wm*128+64..127 ----------------
    if (kt + 1 < NT) {  // stage B(kt+1) half 1
      gld16(Bg + (long)2 * 64 * ldab + (long)(kt + 1) * 128, BoS + 16384);
      gld16(Bg + (long)3 * 64 * ldab + (long)(kt + 1) * 128, BoS + 24576);
    }
#pragma unroll
    for (int mi = 0; mi < 4; mi++)
#pragma unroll
      for (int kk = 0; kk < 2; kk++)
        af[mi][kk] = *(const bf16x8*)&Ac[(wm * 128 + 64 + mi * 16 + l16) * 64 +
                                         ((kk * 32 + quad * 8) ^ sx)];
    // all Ac ds_reads (this tile, all waves) retired -> safe to overwrite Ac
    asm volatile("s_waitcnt lgkmcnt(0)" ::: "memory");
    __builtin_amdgcn_sched_barrier(0);
    __builtin_amdgcn_s_barrier();
    __builtin_amdgcn_sched_barrier(0);
#pragma unroll
    for (int n = 0; n < 4; n++) {
      if (n == 1 && kt + 2 < NT) {  // stage A(kt+2) half 0 into current buf
        gld16(Ag + (long)(kt + 2) * 128, AcS);
        gld16(Ag + (long)64 * ldab + (long)(kt + 2) * 128, AcS + 8192);
      }
      if (n == 2 && kt + 2 < NT) {  // stage A(kt+2) half 1
        gld16(Ag + (long)2 * 64 * ldab + (long)(kt + 2) * 128, AcS + 16384);
        gld16(Ag + (long)3 * 64 * ldab + (long)(kt + 2) * 128, AcS + 24576);
      }
      __builtin_amdgcn_s_setprio(1);
#pragma unroll
      for (int mi = 0; mi < 4; mi++)
#pragma unroll
        for (int kk = 0; kk < 2; kk++)
          acc[4 + mi][n] = mfma16(af[mi][kk], bfr[n][kk], acc[4 + mi][n]);
      __builtin_amdgcn_s_setprio(0);
    }
  };

  for (int kt = 0; kt < NT; kt += 2) {
    tile(kt, A0, B0, A0c, B1c, false);
    tile(kt + 1, A1, B1, A1c, B0c, kt + 2 == NT);
  }

  if constexpr (EPI == G_RELU_BF16) {
#pragma unroll
    for (int m = 0; m < 8; m++)
#pragma unroll
      for (int n = 0; n < 4; n++)
#pragma unroll
        for (int r = 0; r < 4; r++) {
          int row = row0 + wm * 128 + m * 16 + quad * 4 + r;
          int col = col0 + wn * 64 + n * 16 + l16;
          float v = acc[m][n][r] + bias[col];
          Cb[(long)row * ldc + col] = (bf16)fmaxf(v, 0.f);
        }
  } else {  // G_QKV scatter; `which` block-uniform (256 | 1024)
    const int which = col0 >> 10;
    if (which == 2) {
      // V: transpose via LDS (own XOR swizzle), coalesced Vt stores.
      asm volatile("s_waitcnt lgkmcnt(0) vmcnt(0)" ::: "memory");
      __builtin_amdgcn_s_barrier();  // K-loop LDS fully done in all waves
      bf16* T = S;  // 256 cols x 256 rows bf16 = 128 KB
#pragma unroll
      for (int m = 0; m < 8; m++)
#pragma unroll
        for (int n = 0; n < 4; n++)
#pragma unroll
          for (int r = 0; r < 4; r++) {
            int row_l = wm * 128 + m * 16 + quad * 4 + r;
            int col_l = wn * 64 + n * 16 + l16;
            float t = acc[m][n][r] + bias[col0 + col_l];
            T[col_l * 256 + (row_l ^ ((col_l & 7) << 4))] = (bf16)t;
          }
      __syncthreads();
      const int b_ = row0 >> 10;
      const int s0 = row0 & 1023;
#pragma unroll
      for (int g = 0; g < 8; g++) {
        int col_l = wave * 32 + g * 4 + quad;
        int nn = (col0 + col_l) & 1023;
        int h_ = nn >> 6, d_ = nn & 63;
#pragma unroll
        for (int half = 0; half < 2; half++) {
          int sl = l16 * 8 + half * 128;
          bf16x8 vv = *(const bf16x8*)&T[col_l * 256 + (sl ^ ((col_l & 7) << 4))];
          *(bf16x8*)&Vt[(((long)(b_ * H_ + h_)) * DH_ + d_) * S_ + s0 + sl] = vv;
        }
      }
    } else {
#pragma unroll
      for (int m = 0; m < 8; m++)
#pragma unroll
        for (int n = 0; n < 4; n++)
#pragma unroll
          for (int r = 0; r < 4; r++) {
            int row = row0 + wm * 128 + m * 16 + quad * 4 + r;
            int col = col0 + wn * 64 + n * 16 + l16;
            float t = acc[m][n][r] + bias[col];
            int b_ = row >> 10, s_ = row & 1023;
            int nn = col & 1023;
            int h_ = nn >> 6, d_ = nn & 63;
            long q = (((long)(b_ * H_ + h_)) * S_ + s_) * DH_ + d_;
            if (which == 0) Qh[q] = (bf16)t;
            else Kh[q] = (bf16)t;
          }
    }
  }
}

// ------------------------------------------- 128x64 pipelined GEMM (NT)
// For the N=1024 GEMMs (W_o, FFN2): counted-vmcnt + full swizzle, 4 waves
// (2Mx2N, 64x32 each), LDS 48 KB -> grid 512 blocks = 2/CU.
// Instr counts: A=4, B=2 gld16/tile; entry outstanding = 10, vmcnt(4)
// drains {A(kt),B(kt)} leaving A(kt+1)'s 4; last tile vmcnt(0).
// C = A*B^T + bias + res (fp32 out).
__global__ __launch_bounds__(256, 2) void gemm128p(
    const bf16* __restrict__ A, const bf16* __restrict__ Bm,
    float* __restrict__ Cf, const float* __restrict__ bias,
    const float* __restrict__ res, int K, int ldc) {
  __shared__ bf16 S[24576];  // 48 KB: A0(16K)|A1(16K)|B0(8K)|B1(8K)
  bf16* A0 = S;
  bf16* A1 = S + 8192;
  bf16* B0 = S + 16384;
  bf16* B1 = S + 20480;
  const int tid = threadIdx.x, lane = tid & 63, wave = tid >> 6;
  const int quad = lane >> 4, l16 = lane & 15;
  const int wm = wave >> 1, wn = wave & 1;
  const int sx = (l16 & 7) << 3;
  const int row0 = blockIdx.y * 128, col0 = blockIdx.x * 64;
  const int NT = K >> 6;

  const long ldab = (long)K * 2;
  const int cbs = (((tid & 7) ^ ((tid >> 3) & 7))) * 16;
  const char* Ag = (const char*)A + (long)(row0 + (tid >> 3)) * ldab + cbs;
  const char* Bg = (const char*)Bm + (long)(col0 + (tid >> 3)) * ldab + cbs;
  char* A0c = (char*)A0 + tid * 16;
  char* A1c = (char*)A1 + tid * 16;
  char* B0c = (char*)B0 + tid * 16;
  char* B1c = (char*)B1 + tid * 16;

  f32x4 acc[4][2];
#pragma unroll
  for (int m = 0; m < 4; m++)
#pragma unroll
    for (int n = 0; n < 2; n++) acc[m][n] = (f32x4){0.f, 0.f, 0.f, 0.f};

  // prologue: A(0) 4, B(0) 2, A(1) 4 -> 10 outstanding
#pragma unroll
  for (int c = 0; c < 4; c++) gld16(Ag + (long)c * 32 * ldab, A0c + c * 4096);
#pragma unroll
  for (int c = 0; c < 2; c++) gld16(Bg + (long)c * 32 * ldab, B0c + c * 4096);
#pragma unroll
  for (int c = 0; c < 4; c++) gld16(Ag + (long)c * 32 * ldab + 128, A1c + c * 4096);

  auto tile = [&](int kt, const bf16* Ac, const bf16* Bc, char* AcS, char* BoS,
                  bool last) {
    if (last)
      asm volatile("s_waitcnt vmcnt(0)" ::: "memory");
    else
      asm volatile("s_waitcnt vmcnt(4)" ::: "memory");
    __builtin_amdgcn_sched_barrier(0);
    __builtin_amdgcn_s_barrier();
    __builtin_amdgcn_sched_barrier(0);
    // stage B(kt+1) -> other B buffer (2 instrs)
    if (kt + 1 < NT) {
      gld16(Bg + (long)(kt + 1) * 128, BoS);
      gld16(Bg + (long)32 * ldab + (long)(kt + 1) * 128, BoS + 4096);
    }
    // all fragment reads (8 A + 4 B ds_read_b128)
    bf16x8 af[4][2], bfr[2][2];
#pragma unroll
    for (int mi = 0; mi < 4; mi++)
#pragma unroll
      for (int kk = 0; kk < 2; kk++)
        af[mi][kk] = *(const bf16x8*)&Ac[(wm * 64 + mi * 16 + l16) * 64 +
                                         ((kk * 32 + quad * 8) ^ sx)];
#pragma unroll
    for (int nj = 0; nj < 2; nj++)
#pragma unroll
      for (int kk = 0; kk < 2; kk++)
        bfr[nj][kk] = *(const bf16x8*)&Bc[(wn * 32 + nj * 16 + l16) * 64 +
                                          ((kk * 32 + quad * 8) ^ sx)];
    // consumption fence: reads retired -> buffers reusable after barrier
    asm volatile("s_waitcnt lgkmcnt(0)" ::: "memory");
    __builtin_amdgcn_sched_barrier(0);
    __builtin_amdgcn_s_barrier();
    __builtin_amdgcn_sched_barrier(0);
    // stage A(kt+2) into the just-freed current A buffer (4 instrs)
    if (kt + 2 < NT) {
#pragma unroll
      for (int c = 0; c < 4; c++)
        gld16(Ag + (long)c * 32 * ldab + (long)(kt + 2) * 128, AcS + c * 4096);
    }
    __builtin_amdgcn_s_setprio(1);
#pragma unroll
    for (int mi = 0; mi < 4; mi++)
#pragma unroll
      for (int nj = 0; nj < 2; nj++)
#pragma unroll
        for (int kk = 0; kk < 2; kk++)
          acc[mi][nj] = mfma16(af[mi][kk], bfr[nj][kk], acc[mi][nj]);
    __builtin_amdgcn_s_setprio(0);
  };

  for (int kt = 0; kt < NT; kt += 2) {
    tile(kt, A0, B0, A0c, B1c, false);
    tile(kt + 1, A1, B1, A1c, B0c, kt + 2 == NT);
  }

#pragma unroll
  for (int mi = 0; mi < 4; mi++)
#pragma unroll
    for (int nj = 0; nj < 2; nj++)
#pragma unroll
      for (int r = 0; r < 4; r++) {
        int row = row0 + wm * 64 + mi * 16 + quad * 4 + r;
        int col = col0 + wn * 32 + nj * 16 + l16;
        Cf[(long)row * ldc + col] =
            acc[mi][nj][r] + bias[col] + res[(long)row * ldc + col];
      }
}

// --------------------------------------------------- fused attention, pass 1
__global__ __launch_bounds__(256, 2) void attn_pass1(
    const bf16* __restrict__ Q, const bf16* __restrict__ K,
    const float* __restrict__ mask, float* __restrict__ rowsum) {
  __shared__ bf16 Qs[128 * 64];
  __shared__ bf16 Ks[128 * 64];
  const int tid = threadIdx.x, lane = tid & 63, wave = tid >> 6;
  const int quad = lane >> 4, l16 = lane & 15;
  const int q0 = blockIdx.x * 128, bh = blockIdx.y;
  const bf16* Qb = Q + ((long)bh * S_ + q0) * DH_;
  const bf16* Kb = K + (long)bh * S_ * DH_;

  {
    const char* g = (const char*)Qb + wave * 4096 + lane * 16;
    char* l = (char*)Qs + wave * 4096 + lane * 16;
#pragma unroll
    for (int c = 0; c < 4; c++) gld16(g + c * 1024, l + c * 1024);
  }

  float rs[2][4];
#pragma unroll
  for (int i = 0; i < 2; i++)
#pragma unroll
    for (int r = 0; r < 4; r++) rs[i][r] = 0.f;

  for (int t = 0; t < 8; t++) {
    __syncthreads();
    {
      const char* g = (const char*)Kb + (long)t * 16384 + wave * 4096 + lane * 16;
      char* l = (char*)Ks + wave * 4096 + lane * 16;
#pragma unroll
      for (int c = 0; c < 4; c++) gld16(g + c * 1024, l + c * 1024);
    }
    __syncthreads();
    f32x4 acc[2][8];
#pragma unroll
    for (int i = 0; i < 2; i++)
#pragma unroll
      for (int j = 0; j < 8; j++) acc[i][j] = (f32x4){0.f, 0.f, 0.f, 0.f};
#pragma unroll
    for (int kk = 0; kk < 2; kk++) {
      bf16x8 af[2], bfr[8];
#pragma unroll
      for (int i = 0; i < 2; i++)
        af[i] = *(const bf16x8*)&Qs[(wave * 32 + i * 16 + l16) * 64 + kk * 32 + quad * 8];
#pragma unroll
      for (int j = 0; j < 8; j++)
        bfr[j] = *(const bf16x8*)&Ks[(j * 16 + l16) * 64 + kk * 32 + quad * 8];
#pragma unroll
      for (int i = 0; i < 2; i++)
#pragma unroll
        for (int j = 0; j < 8; j++) acc[i][j] = mfma16(af[i], bfr[j], acc[i][j]);
    }
#pragma unroll
    for (int i = 0; i < 2; i++)
#pragma unroll
      for (int j = 0; j < 8; j++)
#pragma unroll
        for (int r = 0; r < 4; r++) {
          int qr = q0 + wave * 32 + i * 16 + quad * 4 + r;
          int gcol = t * 128 + j * 16 + l16;
          float sv = acc[i][j][r] * 0.125f + mask[(long)qr * S_ + gcol];
          rs[i][r] += __expf(sv);
        }
  }
#pragma unroll
  for (int i = 0; i < 2; i++)
#pragma unroll
    for (int r = 0; r < 4; r++) {
      float v = rs[i][r];
      v += __shfl_xor(v, 1);
      v += __shfl_xor(v, 2);
      v += __shfl_xor(v, 4);
      v += __shfl_xor(v, 8);
      if (l16 == 0)
        rowsum[(long)bh * S_ + q0 + wave * 32 + i * 16 + quad * 4 + r] = v;
    }
}

// --------------------------------------------------- fused attention, pass 2
__global__ __launch_bounds__(256, 2) void attn_pass2(
    const bf16* __restrict__ Q, const bf16* __restrict__ K,
    const bf16* __restrict__ V, const float* __restrict__ mask,
    const float* __restrict__ rowsum, float* __restrict__ W,
    bf16* __restrict__ ctxb) {
  __shared__ bf16 Qs[128 * 64];
  __shared__ bf16 Ks[128 * 64];
  __shared__ bf16 Ps[128 * 136];
  const int tid = threadIdx.x, lane = tid & 63, wave = tid >> 6;
  const int quad = lane >> 4, l16 = lane & 15;
  const int q0 = blockIdx.x * 128, bh = blockIdx.y;
  const bf16* Qb = Q + ((long)bh * S_ + q0) * DH_;
  const bf16* Kb = K + (long)bh * S_ * DH_;
  const bf16* Vb = V + (long)bh * DH_ * S_;

  float rinv[2][4];
#pragma unroll
  for (int i = 0; i < 2; i++)
#pragma unroll
    for (int r = 0; r < 4; r++)
      rinv[i][r] =
          1.0f / rowsum[(long)bh * S_ + q0 + wave * 32 + i * 16 + quad * 4 + r];

  {
    const char* g = (const char*)Qb + wave * 4096 + lane * 16;
    char* l = (char*)Qs + wave * 4096 + lane * 16;
#pragma unroll
    for (int c = 0; c < 4; c++) gld16(g + c * 1024, l + c * 1024);
  }

  f32x4 cacc[2][4];
#pragma unroll
  for (int i = 0; i < 2; i++)
#pragma unroll
    for (int j = 0; j < 4; j++) cacc[i][j] = (f32x4){0.f, 0.f, 0.f, 0.f};

  for (int t = 0; t < 8; t++) {
    __syncthreads();
    {
      const char* g = (const char*)Kb + (long)t * 16384 + wave * 4096 + lane * 16;
      char* l = (char*)Ks + wave * 4096 + lane * 16;
#pragma unroll
      for (int c = 0; c < 4; c++) gld16(g + c * 1024, l + c * 1024);
    }
    __syncthreads();
    f32x4 acc[2][8];
#pragma unroll
    for (int i = 0; i < 2; i++)
#pragma unroll
      for (int j = 0; j < 8; j++) acc[i][j] = (f32x4){0.f, 0.f, 0.f, 0.f};
#pragma unroll
    for (int kk = 0; kk < 2; kk++) {
      bf16x8 af[2], bfr[8];
#pragma unroll
      for (int i = 0; i < 2; i++)
        af[i] = *(const bf16x8*)&Qs[(wave * 32 + i * 16 + l16) * 64 + kk * 32 + quad * 8];
#pragma unroll
      for (int j = 0; j < 8; j++)
        bfr[j] = *(const bf16x8*)&Ks[(j * 16 + l16) * 64 + kk * 32 + quad * 8];
#pragma unroll
      for (int i = 0; i < 2; i++)
#pragma unroll
        for (int j = 0; j < 8; j++) acc[i][j] = mfma16(af[i], bfr[j], acc[i][j]);
    }
#pragma unroll
    for (int i = 0; i < 2; i++)
#pragma unroll
      for (int j = 0; j < 8; j++)
#pragma unroll
        for (int r = 0; r < 4; r++) {
          int ql = wave * 32 + i * 16 + quad * 4 + r;
          int qr = q0 + ql;
          int col = j * 16 + l16, gcol = t * 128 + col;
          float u = __expf(acc[i][j][r] * 0.125f + mask[(long)qr * S_ + gcol]) *
                    rinv[i][r];
          __builtin_nontemporal_store(u, &W[((long)bh * S_ + qr) * S_ + gcol]);
          Ps[ql * 136 + col] = (bf16)u;
        }
    __syncthreads();
#pragma unroll
    for (int kk = 0; kk < 4; kk++) {
      bf16x8 pf[2], vf[4];
#pragma unroll
      for (int i = 0; i < 2; i++)
        pf[i] = *(const bf16x8*)&Ps[(wave * 32 + i * 16 + l16) * 136 + kk * 32 + quad * 8];
#pragma unroll
      for (int j = 0; j < 4; j++)
        vf[j] = *(const bf16x8*)(Vb + (long)(j * 16 + l16) * S_ + t * 128 +
                                 kk * 32 + quad * 8);
#pragma unroll
      for (int i = 0; i < 2; i++)
#pragma unroll
        for (int j = 0; j < 4; j++) cacc[i][j] = mfma16(pf[i], vf[j], cacc[i][j]);
    }
  }
  const int b_ = bh >> 4, h_ = bh & 15;
#pragma unroll
  for (int i = 0; i < 2; i++)
#pragma unroll
    for (int j = 0; j < 4; j++)
#pragma unroll
      for (int r = 0; r < 4; r++) {
        int qr = q0 + wave * 32 + i * 16 + quad * 4 + r;
        ctxb[((long)b_ * S_ + qr) * E_ + h_ * 64 + j * 16 + l16] =
            (bf16)cacc[i][j][r];
      }
}

// ------------------------------------------------------- layernorm (single in)
__global__ __launch_bounds__(256) void ln_kernel(
    const float* __restrict__ a, const float* __restrict__ g,
    const float* __restrict__ beta, float* __restrict__ outf,
    bf16* __restrict__ outb) {
  const int tid = threadIdx.x;
  const int wave = tid >> 6, lane = tid & 63;
  long base = (long)blockIdx.x * E_ + tid * 4;
  float4 x = *(const float4*)(a + base);
  float s = x.x + x.y + x.z + x.w;
  float sq = x.x * x.x + x.y * x.y + x.z * x.z + x.w * x.w;
#pragma unroll
  for (int o = 32; o; o >>= 1) { s += __shfl_xor(s, o); sq += __shfl_xor(sq, o); }
  __shared__ float rs[4], rq[4];
  if (!lane) { rs[wave] = s; rq[wave] = sq; }
  __syncthreads();
  s = rs[0] + rs[1] + rs[2] + rs[3];
  sq = rq[0] + rq[1] + rq[2] + rq[3];
  float mu = s * (1.f / E_);
  float var = sq * (1.f / E_) - mu * mu;
  float rstd = rsqrtf(var + 1e-5f);
  int c = tid * 4;
  float4 gg = *(const float4*)(g + c);
  float4 bb = *(const float4*)(beta + c);
  float o0 = (x.x - mu) * rstd * gg.x + bb.x;
  float o1 = (x.y - mu) * rstd * gg.y + bb.y;
  float o2 = (x.z - mu) * rstd * gg.z + bb.z;
  float o3 = (x.w - mu) * rstd * gg.w + bb.w;
  if (outf) *(float4*)(outf + base) = make_float4(o0, o1, o2, o3);
  if (outb) {
    bf16x4 ob = {(bf16)o0, (bf16)o1, (bf16)o2, (bf16)o3};
    *(bf16x4*)(outb + base) = ob;
  }
}

// ---------------------------------------------------------------- launch
extern "C" void kernel_launch(void* const* d_in, const int* in_sizes, int n_in,
                              void* d_out, int out_size, void* d_ws, size_t ws_size,
                              hipStream_t stream) {
  const float* src   = (const float*)d_in[0];
  const float* mask  = (const float*)d_in[1];
  const float* w_qkv = (const float*)d_in[2];
  const float* b_qkv = (const float*)d_in[3];
  const float* w_o   = (const float*)d_in[4];
  const float* b_o   = (const float*)d_in[5];
  const float* w1    = (const float*)d_in[6];
  const float* b1    = (const float*)d_in[7];
  const float* w2    = (const float*)d_in[8];
  const float* b2    = (const float*)d_in[9];
  const float* ln1g  = (const float*)d_in[10];
  const float* ln1b  = (const float*)d_in[11];
  const float* ln2g  = (const float*)d_in[12];
  const float* ln2b  = (const float*)d_in[13];

  float* out = (float*)d_out;
  float* attnW = out + TOK * E_;  // [B,H,S,S] fp32 (output 1)

  char* w = (char*)d_ws;
  auto alloc = [&](size_t bytes) {
    void* p = w;
    w += (bytes + 255) & ~(size_t)255;
    return p;
  };
  bf16* srcb  = (bf16*)alloc(TOK * E_ * 2);
  bf16* wqkvb = (bf16*)alloc((size_t)3 * E_ * E_ * 2);
  bf16* wob   = (bf16*)alloc((size_t)E_ * E_ * 2);
  bf16* w1b   = (bf16*)alloc((size_t)F_ * E_ * 2);
  bf16* w2b   = (bf16*)alloc((size_t)E_ * F_ * 2);
  bf16* Qh    = (bf16*)alloc((size_t)B_ * H_ * S_ * DH_ * 2);
  bf16* Kh    = (bf16*)alloc((size_t)B_ * H_ * S_ * DH_ * 2);
  bf16* Vt    = (bf16*)alloc((size_t)B_ * H_ * DH_ * S_ * 2);
  bf16* ctxb  = (bf16*)alloc(TOK * E_ * 2);
  float* attn_out = (float*)alloc(TOK * E_ * 4);
  float* x1f  = (float*)alloc(TOK * E_ * 4);
  bf16* x1b   = (bf16*)alloc(TOK * E_ * 2);
  bf16* h1b   = (bf16*)alloc(TOK * (size_t)F_ * 2);
  float* ffn2 = (float*)alloc(TOK * E_ * 4);
  float* rowsum = (float*)alloc((size_t)B_ * H_ * S_ * 4);

  f2b_all<<<8192, 256, 0, stream>>>(src, srcb, w_qkv, wqkvb, w_o, wob,
                                    w1, w1b, w2, w2b);

  // QKV projection -> Qh/Kh/Vt  (256-tile pipelined kernel, grid 12x16)
  gemm256<G_QKV><<<dim3(3 * E_ / 256, TOK / 256), 512, 0, stream>>>(
      srcb, wqkvb, nullptr, Qh, Kh, Vt, b_qkv, E_, 0);

  // fused attention
  attn_pass1<<<dim3(S_ / 128, B_ * H_), 256, 0, stream>>>(Qh, Kh, mask, rowsum);
  attn_pass2<<<dim3(S_ / 128, B_ * H_), 256, 0, stream>>>(Qh, Kh, Vt, mask,
                                                          rowsum, attnW, ctxb);

  // attn_out = ctx W_o^T + b_o + src  (counted+swizzled 128x64, grid 16x32)
  gemm128p<<<dim3(E_ / 64, TOK / 128), 256, 0, stream>>>(
      ctxb, wob, attn_out, b_o, src, E_, E_);

  // x1 = LN(attn_out)
  ln_kernel<<<TOK, 256, 0, stream>>>(attn_out, ln1g, ln1b, x1f, x1b);

  // h1 = relu(x1 W1^T + b1)  (256-tile pipelined kernel, grid 16x16)
  gemm256<G_RELU_BF16><<<dim3(F_ / 256, TOK / 256), 512, 0, stream>>>(
      x1b, w1b, h1b, nullptr, nullptr, nullptr, b1, E_, F_);

  // ffn2 = h1 W2^T + b2 + x1  (counted+swizzled 128x64, grid 16x32)
  gemm128p<<<dim3(E_ / 64, TOK / 128), 256, 0, stream>>>(
      h1b, w2b, ffn2, b2, x1f, F_, E_);

  // out = LN(ffn2)
  ln_kernel<<<TOK, 256, 0, stream>>>(ffn2, ln2g, ln2b, out, nullptr);
}